// Round 1
// baseline (649.781 us; speedup 1.0000x reference)
//
#include <hip/hip_runtime.h>
#include <hip/hip_bf16.h>

// ---------------------------------------------------------------------------
// Fused windowed attention: qkv projection (bf16 MFMA) + bias + focus mask +
// softmax + PV, one workgroup per (b, hw) block of 64 tokens.
//   x:        (2,1024,64,512) f32
//   w_qkv:    (1536,512)      f32   (rows 0..511=Q, 512..1023=K, 1024..1535=V)
//   pos_bias: (8,64,64)       f32
//   mask:     (2,) bool/int
//   out:      (2,1024,64,512) f32
// ---------------------------------------------------------------------------

typedef __attribute__((ext_vector_type(4))) float f32x4;
typedef __attribute__((ext_vector_type(8))) short s16x8;

#define DIM 512
#define NTOK 64

__device__ __forceinline__ short f2bf(float f) {
    // round-to-nearest-even fp32 -> bf16 (inputs are finite)
    unsigned int u = __builtin_bit_cast(unsigned int, f);
    u += 0x7fffu + ((u >> 16) & 1u);
    return (short)(u >> 16);
}

// LDS byte addresses with XOR swizzle (16B granularity within 128B groups)
__device__ __forceinline__ int xaddr(int row, int kb) {   // X tile: 64x512 bf16 (1024B rows)
    return (row << 10) + (kb ^ ((row & 7) << 4));
}
__device__ __forceinline__ int taddr(int row, int kb) {   // 64x64 bf16 tile (128B rows)
    return (row << 7) + (kb ^ ((row & 7) << 4));
}

template<int WB16>
__device__ __forceinline__ s16x8 wfrag(const unsigned short* __restrict__ wb,
                                       const float* __restrict__ w,
                                       int row, int k0) {
    if constexpr (WB16) {
        return *(const s16x8*)(wb + (size_t)row * DIM + k0);
    } else {
        const float* p = w + (size_t)row * DIM + k0;
        float4 u0 = *(const float4*)p;
        float4 u1 = *(const float4*)(p + 4);
        float sc = (row < 512) ? 0.125f : 1.0f;   // fold q-scale into Wq
        s16x8 v;
        v[0] = f2bf(u0.x * sc); v[1] = f2bf(u0.y * sc);
        v[2] = f2bf(u0.z * sc); v[3] = f2bf(u0.w * sc);
        v[4] = f2bf(u1.x * sc); v[5] = f2bf(u1.y * sc);
        v[6] = f2bf(u1.z * sc); v[7] = f2bf(u1.w * sc);
        return v;
    }
}

__global__ void conv_w(const float* __restrict__ w, unsigned short* __restrict__ wb) {
    int i = (blockIdx.x * 256 + threadIdx.x) * 4;
    float4 v = *(const float4*)(w + i);
    float sc = (i < 512 * 512) ? 0.125f : 1.0f;   // rows 0..511 are Wq: fold scale
    ushort4 r;
    r.x = (unsigned short)f2bf(v.x * sc);
    r.y = (unsigned short)f2bf(v.y * sc);
    r.z = (unsigned short)f2bf(v.z * sc);
    r.w = (unsigned short)f2bf(v.w * sc);
    *(ushort4*)(wb + i) = r;
}

template<int WB16>
__global__ __launch_bounds__(256, 1)
void attn_fused(const float* __restrict__ x,
                const float* __restrict__ w,
                const unsigned short* __restrict__ wb,
                const float* __restrict__ pb,
                const unsigned int* __restrict__ mk,
                float* __restrict__ out)
{
    extern __shared__ char smem[];
    const int tid  = threadIdx.x;
    const int lane = tid & 63;
    const int wave = tid >> 6;
    const int g    = lane >> 4;
    const int c    = lane & 15;
    const int bs   = blockIdx.x;
    const int b    = bs >> 10;

    // robust focus_present_mask decode (int32 [0,1] or packed bool bytes)
    unsigned int m0 = mk[0], m1 = mk[1];
    bool focused;
    if (m0 <= 1u && m1 <= 1u) focused = ((b == 0) ? m0 : m1) != 0u;
    else                      focused = ((const unsigned char*)mk)[b] != 0;

    const float* xblk   = x   + (size_t)bs * (NTOK * DIM);
    float*       outblk = out + (size_t)bs * (NTOK * DIM);
    char* bufQ = smem + 65536 + wave * 16384;   // q, later vT
    char* bufK = bufQ + 8192;                   // k, later attn

    // ---- staging helpers: X chunk = 64 rows x 128 cols fp32 -> bf16 LDS ----
    auto loadc = [&](int cc, float4 (&st)[8]) {
        #pragma unroll
        for (int u = 0; u < 4; ++u) {
            int idx = u * 256 + tid;
            int row = idx >> 4;
            int cp  = idx & 15;
            const float* gp = xblk + row * DIM + cc * 128 + cp * 8;
            st[2*u]     = *(const float4*)gp;
            st[2*u + 1] = *(const float4*)(gp + 4);
        }
    };
    auto writec = [&](int cc, float4 (&st)[8]) {
        #pragma unroll
        for (int u = 0; u < 4; ++u) {
            int idx = u * 256 + tid;
            int row = idx >> 4;
            int cp  = idx & 15;
            s16x8 v;
            v[0] = f2bf(st[2*u].x);   v[1] = f2bf(st[2*u].y);
            v[2] = f2bf(st[2*u].z);   v[3] = f2bf(st[2*u].w);
            v[4] = f2bf(st[2*u+1].x); v[5] = f2bf(st[2*u+1].y);
            v[6] = f2bf(st[2*u+1].z); v[7] = f2bf(st[2*u+1].w);
            *(s16x8*)(smem + xaddr(row, cc * 256 + cp * 16)) = v;
        }
    };

    // ---- MFMA step helpers ----
    // C = A(64xK) . B(64xK)^T : A rows from LDS X, B rows from W (global)
    auto g1step = [&](f32x4 (&acc)[4][4], int ks, int wbase) {
        s16x8 af[4], bfr[4];
        #pragma unroll
        for (int tr = 0; tr < 4; ++tr)
            af[tr] = *(const s16x8*)(smem + xaddr(tr*16 + c, ks*64 + g*16));
        #pragma unroll
        for (int tc = 0; tc < 4; ++tc)
            bfr[tc] = wfrag<WB16>(wb, w, wbase + tc*16 + c, ks*32 + g*8);
        #pragma unroll
        for (int tr = 0; tr < 4; ++tr)
            #pragma unroll
            for (int tc = 0; tc < 4; ++tc)
                acc[tr][tc] = __builtin_amdgcn_mfma_f32_16x16x32_bf16(
                                  af[tr], bfr[tc], acc[tr][tc], 0, 0, 0);
    };
    // vT = Wv(64xK) . X(64xK)^T : A rows from W (global), B rows from LDS X
    auto gvstep = [&](f32x4 (&acc)[4][4], int ks, int wbase) {
        s16x8 af[4], bfr[4];
        #pragma unroll
        for (int tr = 0; tr < 4; ++tr)
            af[tr] = wfrag<WB16>(wb, w, wbase + tr*16 + c, ks*32 + g*8);
        #pragma unroll
        for (int tc = 0; tc < 4; ++tc)
            bfr[tc] = *(const s16x8*)(smem + xaddr(tc*16 + c, ks*64 + g*16));
        #pragma unroll
        for (int tr = 0; tr < 4; ++tr)
            #pragma unroll
            for (int tc = 0; tc < 4; ++tc)
                acc[tr][tc] = __builtin_amdgcn_mfma_f32_16x16x32_bf16(
                                  af[tr], bfr[tc], acc[tr][tc], 0, 0, 0);
    };
    // 64x64 x 64x64^T, both operands in per-wave LDS tiles
    auto gtstep = [&](f32x4 (&acc)[4][4], int ks, const char* bA, const char* bB) {
        s16x8 af[4], bfr[4];
        #pragma unroll
        for (int tr = 0; tr < 4; ++tr)
            af[tr] = *(const s16x8*)(bA + taddr(tr*16 + c, ks*64 + g*16));
        #pragma unroll
        for (int tc = 0; tc < 4; ++tc)
            bfr[tc] = *(const s16x8*)(bB + taddr(tc*16 + c, ks*64 + g*16));
        #pragma unroll
        for (int tr = 0; tr < 4; ++tr)
            #pragma unroll
            for (int tc = 0; tc < 4; ++tc)
                acc[tr][tc] = __builtin_amdgcn_mfma_f32_16x16x32_bf16(
                                  af[tr], bfr[tc], acc[tr][tc], 0, 0, 0);
    };
    auto storetile = [&](char* buf, f32x4 (&acc)[4][4]) {
        #pragma unroll
        for (int tr = 0; tr < 4; ++tr)
            #pragma unroll
            for (int tc = 0; tc < 4; ++tc)
                #pragma unroll
                for (int r = 0; r < 4; ++r) {
                    int row = tr*16 + g*4 + r;
                    int col = tc*16 + c;
                    *(short*)(buf + (row << 7) + (((col*2) ^ ((row & 7) << 4)))) =
                        f2bf(acc[tr][tc][r]);
                }
    };
    auto zacc = [&](f32x4 (&acc)[4][4]) {
        f32x4 z = {0.f, 0.f, 0.f, 0.f};
        #pragma unroll
        for (int tr = 0; tr < 4; ++tr)
            #pragma unroll
            for (int tc = 0; tc < 4; ++tc)
                acc[tr][tc] = z;
    };

    float4 sa[8], sb[8];

    #pragma unroll
    for (int hi = 0; hi < 2; ++hi) {
        const int h = wave + 4 * hi;

        // ---------------- q = X . Wq^T (scale folded into Wq) ----------------
        f32x4 qa[4][4];
        zacc(qa);
        if (hi == 0) {
            // interleave X staging (4 K-chunks, loads issued 2 chunks ahead)
            loadc(0, sa); loadc(1, sb);
            writec(0, sa); loadc(2, sa); __syncthreads();
            g1step(qa, 0, h*64);  g1step(qa, 1, h*64);
            g1step(qa, 2, h*64);  g1step(qa, 3, h*64);
            writec(1, sb); loadc(3, sb); __syncthreads();
            g1step(qa, 4, h*64);  g1step(qa, 5, h*64);
            g1step(qa, 6, h*64);  g1step(qa, 7, h*64);
            writec(2, sa); __syncthreads();
            g1step(qa, 8, h*64);  g1step(qa, 9, h*64);
            g1step(qa, 10, h*64); g1step(qa, 11, h*64);
            writec(3, sb); __syncthreads();
            g1step(qa, 12, h*64); g1step(qa, 13, h*64);
            g1step(qa, 14, h*64); g1step(qa, 15, h*64);
        } else {
            #pragma unroll 4
            for (int ks = 0; ks < 16; ++ks) g1step(qa, ks, h*64);
        }
        storetile(bufQ, qa);

        // ---------------- k = X . Wk^T ----------------
        f32x4 ka[4][4];
        zacc(ka);
        #pragma unroll 4
        for (int ks = 0; ks < 16; ++ks) g1step(ka, ks, 512 + h*64);
        storetile(bufK, ka);

        __syncthreads();

        // ---------------- sim = q . k^T ----------------
        f32x4 sm[4][4];
        zacc(sm);
        gtstep(sm, 0, bufQ, bufK);
        gtstep(sm, 1, bufQ, bufK);

        __syncthreads();   // q/k reads done; buffers can be overwritten

        // ---------------- vT = Wv . X^T (writes bufQ) ----------------
        f32x4 va[4][4];
        zacc(va);
        #pragma unroll 4
        for (int ks = 0; ks < 16; ++ks) gvstep(va, ks, 1024 + h*64);
        storetile(bufQ, va);

        // ---------------- bias + mask + softmax (in registers) ----------------
        const float* pbh = pb + h * 4096;
        #pragma unroll
        for (int tr = 0; tr < 4; ++tr) {
            #pragma unroll
            for (int r = 0; r < 4; ++r) {
                const int i = tr*16 + g*4 + r;
                float v0 = sm[tr][0][r] + pbh[i*64 +  0 + c];
                float v1 = sm[tr][1][r] + pbh[i*64 + 16 + c];
                float v2 = sm[tr][2][r] + pbh[i*64 + 32 + c];
                float v3 = sm[tr][3][r] + pbh[i*64 + 48 + c];
                if (focused) {
                    v0 = (i ==  0 + c) ? v0 : -3.402823466e38f;
                    v1 = (i == 16 + c) ? v1 : -3.402823466e38f;
                    v2 = (i == 32 + c) ? v2 : -3.402823466e38f;
                    v3 = (i == 48 + c) ? v3 : -3.402823466e38f;
                }
                float mx = fmaxf(fmaxf(v0, v1), fmaxf(v2, v3));
                mx = fmaxf(mx, __shfl_xor(mx, 1));
                mx = fmaxf(mx, __shfl_xor(mx, 2));
                mx = fmaxf(mx, __shfl_xor(mx, 4));
                mx = fmaxf(mx, __shfl_xor(mx, 8));
                float p0 = __expf(v0 - mx);
                float p1 = __expf(v1 - mx);
                float p2 = __expf(v2 - mx);
                float p3 = __expf(v3 - mx);
                float s = p0 + p1 + p2 + p3;
                s += __shfl_xor(s, 1);
                s += __shfl_xor(s, 2);
                s += __shfl_xor(s, 4);
                s += __shfl_xor(s, 8);
                float rinv = 1.0f / s;
                sm[tr][0][r] = p0 * rinv;
                sm[tr][1][r] = p1 * rinv;
                sm[tr][2][r] = p2 * rinv;
                sm[tr][3][r] = p3 * rinv;
            }
        }
        storetile(bufK, sm);   // attn (bf16)

        __syncthreads();

        // ---------------- out = attn . v  (A=attn rows, B=vT rows) ----------------
        f32x4 oa[4][4];
        zacc(oa);
        gtstep(oa, 0, bufK, bufQ);
        gtstep(oa, 1, bufK, bufQ);

        #pragma unroll
        for (int tr = 0; tr < 4; ++tr)
            #pragma unroll
            for (int tc = 0; tc < 4; ++tc)
                #pragma unroll
                for (int r = 0; r < 4; ++r) {
                    int i  = tr*16 + g*4 + r;
                    int dh = tc*16 + c;
                    outblk[(size_t)i * DIM + h*64 + dh] = oa[tr][tc][r];
                }

        __syncthreads();
    }
}

extern "C" void kernel_launch(void* const* d_in, const int* in_sizes, int n_in,
                              void* d_out, int out_size, void* d_ws, size_t ws_size,
                              hipStream_t stream)
{
    const float* x  = (const float*)d_in[0];
    const float* w  = (const float*)d_in[1];
    const float* pb = (const float*)d_in[2];
    const unsigned int* mk = (const unsigned int*)d_in[3];
    float* out = (float*)d_out;

    const int LDS = 131072;
    const size_t wbytes = (size_t)1536 * 512 * sizeof(unsigned short);

    if (ws_size >= wbytes) {
        unsigned short* wb = (unsigned short*)d_ws;
        conv_w<<<dim3(768), dim3(256), 0, stream>>>(w, wb);
        hipFuncSetAttribute(reinterpret_cast<const void*>(&attn_fused<1>),
                            hipFuncAttributeMaxDynamicSharedMemorySize, LDS);
        attn_fused<1><<<dim3(2048), dim3(256), LDS, stream>>>(x, w, wb, pb, mk, out);
    } else {
        hipFuncSetAttribute(reinterpret_cast<const void*>(&attn_fused<0>),
                            hipFuncAttributeMaxDynamicSharedMemorySize, LDS);
        attn_fused<0><<<dim3(2048), dim3(256), LDS, stream>>>(x, w, nullptr, pb, mk, out);
    }
}

// Round 2
// 462.318 us; speedup vs baseline: 1.4055x; 1.4055x over previous
//
#include <hip/hip_runtime.h>
#include <hip/hip_bf16.h>

// ---------------------------------------------------------------------------
// Fused windowed attention, round 2: 8 waves/block (1 head/wave), LDS overlay
// to stay at 128 KiB, frag-contiguous pre-swizzled W, focused-batch shortcut.
//   x:        (2,1024,64,512) f32
//   w_qkv:    (1536,512)      f32   (rows 0..511=Q, 512..1023=K, 1024..1535=V)
//   pos_bias: (8,64,64)       f32
//   mask:     (2,) bool/int
//   out:      (2,1024,64,512) f32
// ---------------------------------------------------------------------------

typedef __attribute__((ext_vector_type(4))) float f32x4;
typedef __attribute__((ext_vector_type(8))) short s16x8;

#define DIM 512

__device__ __forceinline__ short f2bf(float f) {
    // round-to-nearest-even fp32 -> bf16 (inputs finite)
    unsigned int u = __builtin_bit_cast(unsigned int, f);
    u += 0x7fffu + ((u >> 16) & 1u);
    return (short)(u >> 16);
}

// LDS byte addresses, XOR swizzle at 16B granularity (kills the 1KiB-stride
// 32-way bank conflict on ds_read_b128 fragment reads, G4)
__device__ __forceinline__ int xaddr(int row, int kb) {   // X: 64x512 bf16, 1024B rows
    return (row << 10) + (kb ^ ((row & 7) << 4));
}
__device__ __forceinline__ int taddr(int row, int kb) {   // 64x64 bf16 tile, 128B rows
    return (row << 7) + (kb ^ ((row & 7) << 4));
}

// ---------------------------------------------------------------------------
// W pre-swizzle: 16B fragment chunk index = (rowblk*16 + ks)*64 + lane
// so a wave's B/A-fragment load of W is one contiguous 1 KiB transaction.
// rowblk = row/16 (96), ks = K-slice of 32 cols (16), lane = g*16 + c where
// row = rowblk*16 + c, cols = ks*32 + g*8 .. +8.  q-scale folded into Wq rows.
// ---------------------------------------------------------------------------
__global__ void conv_w(const float* __restrict__ w, unsigned short* __restrict__ wb) {
    int gid  = blockIdx.x * 256 + threadIdx.x;       // 0 .. 98303
    int lane = gid & 63;
    int ks   = (gid >> 6) & 15;
    int rowblk = gid >> 10;
    int row = rowblk * 16 + (lane & 15);
    int col = ks * 32 + (lane >> 4) * 8;
    const float* p = w + (size_t)row * DIM + col;
    float4 a = *(const float4*)p;
    float4 b = *(const float4*)(p + 4);
    float sc = (row < 512) ? 0.125f : 1.0f;
    s16x8 v;
    v[0] = f2bf(a.x * sc); v[1] = f2bf(a.y * sc);
    v[2] = f2bf(a.z * sc); v[3] = f2bf(a.w * sc);
    v[4] = f2bf(b.x * sc); v[5] = f2bf(b.y * sc);
    v[6] = f2bf(b.z * sc); v[7] = f2bf(b.w * sc);
    *(s16x8*)(wb + (size_t)gid * 8) = v;
}

template<int WB16>
__device__ __forceinline__ s16x8 wfragL(const unsigned short* __restrict__ wb,
                                        const float* __restrict__ w,
                                        int rowblk, int ks, int lane) {
    if constexpr (WB16) {
        return *(const s16x8*)(wb + ((size_t)(rowblk * 16 + ks) * 64 + lane) * 8);
    } else {
        int row = rowblk * 16 + (lane & 15);
        int col = ks * 32 + (lane >> 4) * 8;
        const float* p = w + (size_t)row * DIM + col;
        float4 u0 = *(const float4*)p;
        float4 u1 = *(const float4*)(p + 4);
        float sc = (row < 512) ? 0.125f : 1.0f;
        s16x8 v;
        v[0] = f2bf(u0.x * sc); v[1] = f2bf(u0.y * sc);
        v[2] = f2bf(u0.z * sc); v[3] = f2bf(u0.w * sc);
        v[4] = f2bf(u1.x * sc); v[5] = f2bf(u1.y * sc);
        v[6] = f2bf(u1.z * sc); v[7] = f2bf(u1.w * sc);
        return v;
    }
}

// LDS map (128 KiB total -> 1 block/CU, 8 waves = 2 waves/SIMD):
//   [0, 64K):   X tile 64x512 bf16 (swizzled). After the X-retirement barrier,
//               wave w's 8 KiB sub-slot holds q, later vT  (wave-private).
//   [64K,128K): per-wave 8 KiB slot: k, later attn         (wave-private).
template<int WB16>
__global__ __launch_bounds__(512, 2)
void attn_fused(const float* __restrict__ x,
                const float* __restrict__ w,
                const unsigned short* __restrict__ wb,
                const float* __restrict__ pb,
                const unsigned int* __restrict__ mk,
                float* __restrict__ out)
{
    extern __shared__ char smem[];
    const int tid  = threadIdx.x;
    const int lane = tid & 63;
    const int wave = tid >> 6;          // == head index
    const int g    = lane >> 4;
    const int c    = lane & 15;
    const int bs   = blockIdx.x;
    const int b    = bs >> 10;

    // robust focus_present_mask decode (int32 [0,1] or packed bool bytes)
    unsigned int m0 = mk[0], m1 = mk[1];
    bool focused;
    if (m0 <= 1u && m1 <= 1u) focused = ((b == 0) ? m0 : m1) != 0u;
    else                      focused = ((const unsigned char*)mk)[b] != 0;

    const float* xblk   = x   + (size_t)bs * (64 * DIM);
    float*       outblk = out + (size_t)bs * (64 * DIM);
    char* slotW = smem + 65536 + wave * 8192;   // k -> attn
    char* slotX = smem + wave * 8192;           // q -> vT (after X retirement)

    // ---- staging: X chunk = 64 rows x 128 cols fp32 -> bf16 swizzled LDS ----
    float4 sa[4], sb[4];
    const int srow = tid >> 3;          // 0..63
    const int scp  = tid & 7;           // 0..7 (16 cols each)
    auto loadc = [&](int cc, float4 (&st)[4]) {
        const float* gp = xblk + srow * DIM + cc * 128 + scp * 16;
        st[0] = *(const float4*)gp;
        st[1] = *(const float4*)(gp + 4);
        st[2] = *(const float4*)(gp + 8);
        st[3] = *(const float4*)(gp + 12);
    };
    auto writec = [&](int cc, float4 (&st)[4]) {
        int kb = cc * 256 + scp * 32;   // byte offset in row
        s16x8 v0, v1;
        v0[0] = f2bf(st[0].x); v0[1] = f2bf(st[0].y);
        v0[2] = f2bf(st[0].z); v0[3] = f2bf(st[0].w);
        v0[4] = f2bf(st[1].x); v0[5] = f2bf(st[1].y);
        v0[6] = f2bf(st[1].z); v0[7] = f2bf(st[1].w);
        v1[0] = f2bf(st[2].x); v1[1] = f2bf(st[2].y);
        v1[2] = f2bf(st[2].z); v1[3] = f2bf(st[2].w);
        v1[4] = f2bf(st[3].x); v1[5] = f2bf(st[3].y);
        v1[6] = f2bf(st[3].z); v1[7] = f2bf(st[3].w);
        *(s16x8*)(smem + xaddr(srow, kb))      = v0;
        *(s16x8*)(smem + xaddr(srow, kb + 16)) = v1;
    };

    // ---- MFMA helpers ----
    // C += Xtile(64xK) . W(64xK)^T   (A rows from LDS X, B rows from W)
    auto g1step = [&](f32x4 (&acc)[4][4], int ks, int rblk) {
        s16x8 af[4], bfr[4];
        #pragma unroll
        for (int tr = 0; tr < 4; ++tr)
            af[tr] = *(const s16x8*)(smem + xaddr(tr * 16 + c, ks * 64 + g * 16));
        #pragma unroll
        for (int tc = 0; tc < 4; ++tc)
            bfr[tc] = wfragL<WB16>(wb, w, rblk + tc, ks, lane);
        #pragma unroll
        for (int tr = 0; tr < 4; ++tr)
            #pragma unroll
            for (int tc = 0; tc < 4; ++tc)
                acc[tr][tc] = __builtin_amdgcn_mfma_f32_16x16x32_bf16(
                                  af[tr], bfr[tc], acc[tr][tc], 0, 0, 0);
    };
    // C += Wv(64xK) . Xtile(64xK)^T  (vT = v transposed: rows = head-dim)
    auto gvstep = [&](f32x4 (&acc)[4][4], int ks, int rblk) {
        s16x8 af[4], bfr[4];
        #pragma unroll
        for (int tr = 0; tr < 4; ++tr)
            af[tr] = wfragL<WB16>(wb, w, rblk + tr, ks, lane);
        #pragma unroll
        for (int tc = 0; tc < 4; ++tc)
            bfr[tc] = *(const s16x8*)(smem + xaddr(tc * 16 + c, ks * 64 + g * 16));
        #pragma unroll
        for (int tr = 0; tr < 4; ++tr)
            #pragma unroll
            for (int tc = 0; tc < 4; ++tc)
                acc[tr][tc] = __builtin_amdgcn_mfma_f32_16x16x32_bf16(
                                  af[tr], bfr[tc], acc[tr][tc], 0, 0, 0);
    };
    // C += A(64x64) . B(64x64)^T, both 64x64 LDS tiles (wave-private)
    auto gtstep = [&](f32x4 (&acc)[4][4], int ks, const char* bA, const char* bB) {
        s16x8 af[4], bfr[4];
        #pragma unroll
        for (int tr = 0; tr < 4; ++tr)
            af[tr] = *(const s16x8*)(bA + taddr(tr * 16 + c, ks * 64 + g * 16));
        #pragma unroll
        for (int tc = 0; tc < 4; ++tc)
            bfr[tc] = *(const s16x8*)(bB + taddr(tc * 16 + c, ks * 64 + g * 16));
        #pragma unroll
        for (int tr = 0; tr < 4; ++tr)
            #pragma unroll
            for (int tc = 0; tc < 4; ++tc)
                acc[tr][tc] = __builtin_amdgcn_mfma_f32_16x16x32_bf16(
                                  af[tr], bfr[tc], acc[tr][tc], 0, 0, 0);
    };
    auto storetile = [&](char* buf, f32x4 (&acc)[4][4]) {
        #pragma unroll
        for (int tr = 0; tr < 4; ++tr)
            #pragma unroll
            for (int tc = 0; tc < 4; ++tc)
                #pragma unroll
                for (int r = 0; r < 4; ++r) {
                    int row = tr * 16 + g * 4 + r;
                    int col = tc * 16 + c;
                    *(short*)(buf + (row << 7) + ((col * 2) ^ ((row & 7) << 4))) =
                        f2bf(acc[tr][tc][r]);
                }
    };
    auto zacc = [&](f32x4 (&acc)[4][4]) {
        f32x4 z = {0.f, 0.f, 0.f, 0.f};
        #pragma unroll
        for (int tr = 0; tr < 4; ++tr)
            #pragma unroll
            for (int tc = 0; tc < 4; ++tc)
                acc[tr][tc] = z;
    };

    const int RQ = wave * 4;        // Wq rowblk base for this head
    const int RK = 32 + wave * 4;   // Wk
    const int RV = 64 + wave * 4;   // Wv

    if (focused) {
        // eye mask => attn = I => out = v = X . Wv^T. Skip q/k/sim/softmax/PV.
        f32x4 va[4][4];
        zacc(va);
        loadc(0, sa); loadc(1, sb);
        writec(0, sa); loadc(2, sa); __syncthreads();
        g1step(va, 0, RV);  g1step(va, 1, RV);
        g1step(va, 2, RV);  g1step(va, 3, RV);
        writec(1, sb); loadc(3, sb); __syncthreads();
        g1step(va, 4, RV);  g1step(va, 5, RV);
        g1step(va, 6, RV);  g1step(va, 7, RV);
        writec(2, sa); __syncthreads();
        g1step(va, 8, RV);  g1step(va, 9, RV);
        g1step(va, 10, RV); g1step(va, 11, RV);
        writec(3, sb); __syncthreads();
        g1step(va, 12, RV); g1step(va, 13, RV);
        g1step(va, 14, RV); g1step(va, 15, RV);
        #pragma unroll
        for (int tr = 0; tr < 4; ++tr)
            #pragma unroll
            for (int tc = 0; tc < 4; ++tc)
                #pragma unroll
                for (int r = 0; r < 4; ++r) {
                    int i  = tr * 16 + g * 4 + r;
                    int dh = tc * 16 + c;
                    outblk[(size_t)i * DIM + wave * 64 + dh] = va[tr][tc][r];
                }
        return;
    }

    // ---------------- q,k GEMMs interleaved with X staging ----------------
    f32x4 qa[4][4], ka[4][4];
    zacc(qa); zacc(ka);
    loadc(0, sa); loadc(1, sb);
    writec(0, sa); loadc(2, sa); __syncthreads();
    g1step(qa, 0, RQ); g1step(ka, 0, RK);
    g1step(qa, 1, RQ); g1step(ka, 1, RK);
    g1step(qa, 2, RQ); g1step(ka, 2, RK);
    g1step(qa, 3, RQ); g1step(ka, 3, RK);
    writec(1, sb); loadc(3, sb); __syncthreads();
    g1step(qa, 4, RQ); g1step(ka, 4, RK);
    g1step(qa, 5, RQ); g1step(ka, 5, RK);
    g1step(qa, 6, RQ); g1step(ka, 6, RK);
    g1step(qa, 7, RQ); g1step(ka, 7, RK);
    writec(2, sa); __syncthreads();
    g1step(qa, 8, RQ);  g1step(ka, 8, RK);
    g1step(qa, 9, RQ);  g1step(ka, 9, RK);
    g1step(qa, 10, RQ); g1step(ka, 10, RK);
    g1step(qa, 11, RQ); g1step(ka, 11, RK);
    writec(3, sb); __syncthreads();
    g1step(qa, 12, RQ); g1step(ka, 12, RK);
    g1step(qa, 13, RQ); g1step(ka, 13, RK);
    g1step(qa, 14, RQ); g1step(ka, 14, RK);
    g1step(qa, 15, RQ); g1step(ka, 15, RK);

    storetile(slotW, ka);           // free k registers

    // ---------------- vT = Wv . X^T (last consumer of X) ----------------
    f32x4 va[4][4];
    zacc(va);
    #pragma unroll 4
    for (int ks = 0; ks < 16; ++ks) gvstep(va, ks, RV);

    __syncthreads();                // X retirement: X region becomes slots

    storetile(slotX, qa);           // q -> own X sub-slot (wave-private)

    // ---------------- sim = q . k^T ----------------
    f32x4 sm[4][4];
    zacc(sm);
    gtstep(sm, 0, slotX, slotW);
    gtstep(sm, 1, slotX, slotW);

    // ---------------- bias + softmax (in registers; h = wave) ----------------
    const float* pbh = pb + wave * 4096;
    #pragma unroll
    for (int tr = 0; tr < 4; ++tr) {
        #pragma unroll
        for (int r = 0; r < 4; ++r) {
            const int i = tr * 16 + g * 4 + r;
            float v0 = sm[tr][0][r] + pbh[i * 64 +  0 + c];
            float v1 = sm[tr][1][r] + pbh[i * 64 + 16 + c];
            float v2 = sm[tr][2][r] + pbh[i * 64 + 32 + c];
            float v3 = sm[tr][3][r] + pbh[i * 64 + 48 + c];
            float mx = fmaxf(fmaxf(v0, v1), fmaxf(v2, v3));
            mx = fmaxf(mx, __shfl_xor(mx, 1));
            mx = fmaxf(mx, __shfl_xor(mx, 2));
            mx = fmaxf(mx, __shfl_xor(mx, 4));
            mx = fmaxf(mx, __shfl_xor(mx, 8));
            float p0 = __expf(v0 - mx);
            float p1 = __expf(v1 - mx);
            float p2 = __expf(v2 - mx);
            float p3 = __expf(v3 - mx);
            float s = p0 + p1 + p2 + p3;
            s += __shfl_xor(s, 1);
            s += __shfl_xor(s, 2);
            s += __shfl_xor(s, 4);
            s += __shfl_xor(s, 8);
            float rinv = 1.0f / s;
            sm[tr][0][r] = p0 * rinv;
            sm[tr][1][r] = p1 * rinv;
            sm[tr][2][r] = p2 * rinv;
            sm[tr][3][r] = p3 * rinv;
        }
    }

    storetile(slotW, sm);           // attn overwrites k (consumed by sim)
    storetile(slotX, va);           // vT overwrites q (consumed by sim)

    // ---------------- out = attn . v ----------------
    f32x4 oa[4][4];
    zacc(oa);
    gtstep(oa, 0, slotW, slotX);
    gtstep(oa, 1, slotW, slotX);

    #pragma unroll
    for (int tr = 0; tr < 4; ++tr)
        #pragma unroll
        for (int tc = 0; tc < 4; ++tc)
            #pragma unroll
            for (int r = 0; r < 4; ++r) {
                int i  = tr * 16 + g * 4 + r;
                int dh = tc * 16 + c;
                outblk[(size_t)i * DIM + wave * 64 + dh] = oa[tr][tc][r];
            }
}

extern "C" void kernel_launch(void* const* d_in, const int* in_sizes, int n_in,
                              void* d_out, int out_size, void* d_ws, size_t ws_size,
                              hipStream_t stream)
{
    const float* x  = (const float*)d_in[0];
    const float* w  = (const float*)d_in[1];
    const float* pb = (const float*)d_in[2];
    const unsigned int* mk = (const unsigned int*)d_in[3];
    float* out = (float*)d_out;

    const int LDS = 131072;
    const size_t wbytes = (size_t)1536 * 512 * sizeof(unsigned short);

    if (ws_size >= wbytes) {
        unsigned short* wb = (unsigned short*)d_ws;
        conv_w<<<dim3(384), dim3(256), 0, stream>>>(w, wb);
        hipFuncSetAttribute(reinterpret_cast<const void*>(&attn_fused<1>),
                            hipFuncAttributeMaxDynamicSharedMemorySize, LDS);
        attn_fused<1><<<dim3(2048), dim3(512), LDS, stream>>>(x, w, wb, pb, mk, out);
    } else {
        hipFuncSetAttribute(reinterpret_cast<const void*>(&attn_fused<0>),
                            hipFuncAttributeMaxDynamicSharedMemorySize, LDS);
        attn_fused<0><<<dim3(2048), dim3(512), LDS, stream>>>(x, w, nullptr, pb, mk, out);
    }
}